// Round 1
// baseline (969.636 us; speedup 1.0000x reference)
//
#include <hip/hip_runtime.h>
#include <stdint.h>
#include <stddef.h>

#define B_SZ 32
#define NQ 577
#define CDIM 768
#define NH 12
#define HDIM 64
#define MROWS (B_SZ * NQ)     // 18464
#define VT_STRIDE 640         // padded key-dim stride for V^T (16B aligned, covers kv-tail reads)
#define QT_TILES 37           // ceil(577/16)
#define SCALE_F 0.125f        // 64^-0.5

typedef __bf16 bf16x8 __attribute__((ext_vector_type(8)));
typedef float f32x4 __attribute__((ext_vector_type(4)));
typedef unsigned short u16x8 __attribute__((ext_vector_type(8)));

__device__ __forceinline__ unsigned short f2bf(float f) {
    unsigned int u = __builtin_bit_cast(unsigned int, f);
    return (unsigned short)((u + 0x7fffu + ((u >> 16) & 1u)) >> 16);  // RNE
}

__device__ __forceinline__ f32x4 mfma16(bf16x8 a, bf16x8 b, f32x4 c) {
    return __builtin_amdgcn_mfma_f32_16x16x32_bf16(a, b, c, 0, 0, 0);
}

// load 8 consecutive fp32, convert to bf16x8 fragment
__device__ __forceinline__ bf16x8 cvt8(const float* p) {
    f32x4 v0 = *(const f32x4*)p;
    f32x4 v1 = *(const f32x4*)(p + 4);
    u16x8 u;
    u[0] = f2bf(v0[0]); u[1] = f2bf(v0[1]); u[2] = f2bf(v0[2]); u[3] = f2bf(v0[3]);
    u[4] = f2bf(v1[0]); u[5] = f2bf(v1[1]); u[6] = f2bf(v1[2]); u[7] = f2bf(v1[3]);
    return __builtin_bit_cast(bf16x8, u);
}

// ---------------- Stage 1: QKV = x @ qkv_w^T, scattered into q,k [B,H,N,64] and V^T [B,H,64,VT_STRIDE]
__global__ __launch_bounds__(256) void qkv_gemm(
    const float* __restrict__ x,       // [18464][768]
    const float* __restrict__ w,       // [2304][768]
    unsigned short* __restrict__ qb,
    unsigned short* __restrict__ kb,
    unsigned short* __restrict__ vtb)
{
    const int wv = threadIdx.x >> 6;
    const int lane = threadIdx.x & 63;
    const int lo = lane & 15, hi = lane >> 4;
    const int NT = (3 * CDIM) / 64;        // 36
    const int MT = (MROWS + 63) / 64;      // 289
    int tile = blockIdx.x * 4 + wv;
    if (tile >= MT * NT) return;
    int nt = tile % NT, mt = tile / NT;

    f32x4 acc[4][4];
#pragma unroll
    for (int i = 0; i < 4; ++i)
#pragma unroll
        for (int j = 0; j < 4; ++j) acc[i][j] = (f32x4){0.f, 0.f, 0.f, 0.f};

    int arow[4], bcol[4];
#pragma unroll
    for (int mi = 0; mi < 4; ++mi) {
        int r = mt * 64 + mi * 16 + lo;
        arow[mi] = r < MROWS ? r : MROWS - 1;
    }
#pragma unroll
    for (int ni = 0; ni < 4; ++ni) bcol[ni] = nt * 64 + ni * 16 + lo;

    for (int k0 = 0; k0 < CDIM; k0 += 32) {
        bf16x8 af[4], bfr[4];
#pragma unroll
        for (int mi = 0; mi < 4; ++mi)
            af[mi] = cvt8(x + (size_t)arow[mi] * CDIM + k0 + 8 * hi);
#pragma unroll
        for (int ni = 0; ni < 4; ++ni)
            bfr[ni] = cvt8(w + (size_t)bcol[ni] * CDIM + k0 + 8 * hi);
#pragma unroll
        for (int mi = 0; mi < 4; ++mi)
#pragma unroll
            for (int ni = 0; ni < 4; ++ni)
                acc[mi][ni] = mfma16(af[mi], bfr[ni], acc[mi][ni]);
    }

    int cbase = nt * 64;
    int s = cbase / CDIM;                 // 0:q 1:k 2:v  (uniform per tile)
    int h = (cbase % CDIM) / HDIM;        // uniform per tile
#pragma unroll
    for (int mi = 0; mi < 4; ++mi) {
#pragma unroll
        for (int r = 0; r < 4; ++r) {
            int m = mt * 64 + mi * 16 + hi * 4 + r;
            if (m >= MROWS) continue;
            int b = m / NQ, n = m % NQ;
            size_t bhn = (size_t)(b * NH + h);
#pragma unroll
            for (int ni = 0; ni < 4; ++ni) {
                int d = ni * 16 + lo;
                unsigned short bv = f2bf(acc[mi][ni][r]);
                if (s == 0)      qb[(bhn * NQ + n) * HDIM + d] = bv;
                else if (s == 1) kb[(bhn * NQ + n) * HDIM + d] = bv;
                else             vtb[(bhn * HDIM + d) * VT_STRIDE + n] = bv;
            }
        }
    }
}

// ---------------- Stage 2: flash attention per (b,h,16-row q-tile); 4 waves/block, each its own tile
__global__ __launch_bounds__(256) void attn_fused(
    const unsigned short* __restrict__ qb,
    const unsigned short* __restrict__ kb,
    const unsigned short* __restrict__ vtb,
    const float* __restrict__ mask,     // [12][577][577] fp32
    unsigned short* __restrict__ ob)    // [B][577][768] bf16
{
    __shared__ unsigned short P_lds[4][16][72];  // pad 8 -> stride 144B, 2-way bank alias only
    const int wv = threadIdx.x >> 6;
    const int lane = threadIdx.x & 63;
    const int lo = lane & 15, hi = lane >> 4;
    int bh = blockIdx.x / 10;
    int qt = (blockIdx.x % 10) * 4 + wv;
    bool valid = qt < QT_TILES;
    if (qt > QT_TILES - 1) qt = QT_TILES - 1;
    int h = bh % NH, b = bh / NH;

    const unsigned short* qp = qb + (size_t)bh * NQ * HDIM;
    const unsigned short* kp = kb + (size_t)bh * NQ * HDIM;
    const unsigned short* vp = vtb + (size_t)bh * HDIM * VT_STRIDE;
    const float* mp = mask + (size_t)h * NQ * NQ;

    int qr = qt * 16 + lo; if (qr > NQ - 1) qr = NQ - 1;
    bf16x8 aq0 = *(const bf16x8*)(qp + (size_t)qr * HDIM + 8 * hi);
    bf16x8 aq1 = *(const bf16x8*)(qp + (size_t)qr * HDIM + 32 + 8 * hi);

    float m_run[4], l_run[4];
    f32x4 accO[4];
#pragma unroll
    for (int r = 0; r < 4; ++r) { m_run[r] = -1e30f; l_run[r] = 0.f; }
#pragma unroll
    for (int dj = 0; dj < 4; ++dj) accO[dj] = (f32x4){0.f, 0.f, 0.f, 0.f};

    const int qrowbase = qt * 16 + hi * 4;

    for (int kv0 = 0; kv0 < NQ; kv0 += 64) {
        f32x4 S[4];
#pragma unroll
        for (int nj = 0; nj < 4; ++nj) {
            int kc = kv0 + nj * 16 + lo; if (kc > NQ - 1) kc = NQ - 1;
            bf16x8 bk0 = *(const bf16x8*)(kp + (size_t)kc * HDIM + 8 * hi);
            bf16x8 bk1 = *(const bf16x8*)(kp + (size_t)kc * HDIM + 32 + 8 * hi);
            f32x4 sv = (f32x4){0.f, 0.f, 0.f, 0.f};
            sv = mfma16(aq0, bk0, sv);
            sv = mfma16(aq1, bk1, sv);
            S[nj] = sv;
        }
#pragma unroll
        for (int nj = 0; nj < 4; ++nj) {
            int col = kv0 + nj * 16 + lo;
            if (col < NQ) {
#pragma unroll
                for (int r = 0; r < 4; ++r) {
                    int rowc = qrowbase + r; if (rowc > NQ - 1) rowc = NQ - 1;
                    S[nj][r] = S[nj][r] * SCALE_F + mp[(size_t)rowc * NQ + col];
                }
            } else {
#pragma unroll
                for (int r = 0; r < 4; ++r) S[nj][r] = -1e30f;
            }
        }
#pragma unroll
        for (int r = 0; r < 4; ++r) {
            float mx = fmaxf(fmaxf(S[0][r], S[1][r]), fmaxf(S[2][r], S[3][r]));
            mx = fmaxf(mx, __shfl_xor(mx, 1));
            mx = fmaxf(mx, __shfl_xor(mx, 2));
            mx = fmaxf(mx, __shfl_xor(mx, 4));
            mx = fmaxf(mx, __shfl_xor(mx, 8));
            float mnew = fmaxf(m_run[r], mx);
            float corr = __expf(m_run[r] - mnew);
            m_run[r] = mnew;
            l_run[r] *= corr;
            accO[0][r] *= corr; accO[1][r] *= corr;
            accO[2][r] *= corr; accO[3][r] *= corr;
            float ps = 0.f;
#pragma unroll
            for (int nj = 0; nj < 4; ++nj) {
                float p = __expf(S[nj][r] - mnew);
                ps += p;
                P_lds[wv][hi * 4 + r][nj * 16 + lo] = f2bf(p);
            }
            ps += __shfl_xor(ps, 1);
            ps += __shfl_xor(ps, 2);
            ps += __shfl_xor(ps, 4);
            ps += __shfl_xor(ps, 8);
            l_run[r] += ps;
        }
        __syncthreads();
        bf16x8 pa0 = *(const bf16x8*)(&P_lds[wv][lo][8 * hi]);
        bf16x8 pa1 = *(const bf16x8*)(&P_lds[wv][lo][32 + 8 * hi]);
#pragma unroll
        for (int dj = 0; dj < 4; ++dj) {
            const unsigned short* vrow = vp + (size_t)(dj * 16 + lo) * VT_STRIDE + kv0;
            bf16x8 bv0 = *(const bf16x8*)(vrow + 8 * hi);
            bf16x8 bv1 = *(const bf16x8*)(vrow + 32 + 8 * hi);
            accO[dj] = mfma16(pa0, bv0, accO[dj]);
            accO[dj] = mfma16(pa1, bv1, accO[dj]);
        }
        __syncthreads();
    }

    if (valid) {
#pragma unroll
        for (int r = 0; r < 4; ++r) {
            int row = qt * 16 + hi * 4 + r;
            if (row >= NQ) continue;
            float inv = 1.0f / l_run[r];
            size_t base = ((size_t)b * NQ + row) * CDIM + h * HDIM;
#pragma unroll
            for (int dj = 0; dj < 4; ++dj)
                ob[base + dj * 16 + lo] = f2bf(accO[dj][r] * inv);
        }
    }
}

// ---------------- Stage 3: out = attn_out @ proj_w^T + proj_b (fp32 out)
__global__ __launch_bounds__(256) void proj_gemm(
    const unsigned short* __restrict__ ain,  // [18464][768] bf16
    const float* __restrict__ w,             // [768][768]
    const float* __restrict__ bias,          // [768]
    float* __restrict__ out)                 // [18464][768]
{
    const int wv = threadIdx.x >> 6;
    const int lane = threadIdx.x & 63;
    const int lo = lane & 15, hi = lane >> 4;
    const int NT = CDIM / 64;             // 12
    const int MT = (MROWS + 63) / 64;     // 289
    int tile = blockIdx.x * 4 + wv;
    if (tile >= MT * NT) return;
    int nt = tile % NT, mt = tile / NT;

    f32x4 acc[4][4];
#pragma unroll
    for (int i = 0; i < 4; ++i)
#pragma unroll
        for (int j = 0; j < 4; ++j) acc[i][j] = (f32x4){0.f, 0.f, 0.f, 0.f};

    int arow[4], bcol[4];
#pragma unroll
    for (int mi = 0; mi < 4; ++mi) {
        int r = mt * 64 + mi * 16 + lo;
        arow[mi] = r < MROWS ? r : MROWS - 1;
    }
#pragma unroll
    for (int ni = 0; ni < 4; ++ni) bcol[ni] = nt * 64 + ni * 16 + lo;

    for (int k0 = 0; k0 < CDIM; k0 += 32) {
        bf16x8 af[4], bfr[4];
#pragma unroll
        for (int mi = 0; mi < 4; ++mi)
            af[mi] = *(const bf16x8*)(ain + (size_t)arow[mi] * CDIM + k0 + 8 * hi);
#pragma unroll
        for (int ni = 0; ni < 4; ++ni)
            bfr[ni] = cvt8(w + (size_t)bcol[ni] * CDIM + k0 + 8 * hi);
#pragma unroll
        for (int mi = 0; mi < 4; ++mi)
#pragma unroll
            for (int ni = 0; ni < 4; ++ni)
                acc[mi][ni] = mfma16(af[mi], bfr[ni], acc[mi][ni]);
    }

    float bv[4];
#pragma unroll
    for (int ni = 0; ni < 4; ++ni) bv[ni] = bias[nt * 64 + ni * 16 + lo];
#pragma unroll
    for (int mi = 0; mi < 4; ++mi)
#pragma unroll
        for (int r = 0; r < 4; ++r) {
            int m = mt * 64 + mi * 16 + hi * 4 + r;
            if (m >= MROWS) continue;
#pragma unroll
            for (int ni = 0; ni < 4; ++ni)
                out[(size_t)m * CDIM + nt * 64 + ni * 16 + lo] = acc[mi][ni][r] + bv[ni];
        }
}

extern "C" void kernel_launch(void* const* d_in, const int* in_sizes, int n_in,
                              void* d_out, int out_size, void* d_ws, size_t ws_size,
                              hipStream_t stream) {
    (void)in_sizes; (void)n_in; (void)out_size; (void)ws_size;
    const float* x      = (const float*)d_in[0];
    const float* qkv_w  = (const float*)d_in[1];
    const float* proj_w = (const float*)d_in[2];
    const float* proj_b = (const float*)d_in[3];
    const float* mask   = (const float*)d_in[4];
    float* out = (float*)d_out;

    const size_t qk_elems = (size_t)B_SZ * NH * NQ * HDIM;        // 14,180,352
    const size_t vt_elems = (size_t)B_SZ * NH * HDIM * VT_STRIDE; // 15,728,640
    unsigned short* qbuf  = (unsigned short*)d_ws;
    unsigned short* kbuf  = qbuf + qk_elems;
    unsigned short* vtbuf = kbuf + qk_elems;
    unsigned short* aobuf = vtbuf + vt_elems;
    // total workspace use: ~111 MiB

    qkv_gemm<<<(289 * 36) / 4, 256, 0, stream>>>(x, qkv_w, qbuf, kbuf, vtbuf);
    attn_fused<<<B_SZ * NH * 10, 256, 0, stream>>>(qbuf, kbuf, vtbuf, mask, aobuf);
    proj_gemm<<<(289 * 12) / 4, 256, 0, stream>>>(aobuf, proj_w, proj_b, out);
}

// Round 2
// 505.799 us; speedup vs baseline: 1.9170x; 1.9170x over previous
//
#include <hip/hip_runtime.h>
#include <stdint.h>
#include <stddef.h>

#define B_SZ 32
#define NQ 577
#define CDIM 768
#define NH 12
#define HDIM 64
#define MROWS (B_SZ * NQ)     // 18464
#define KDIM CDIM             // 768 (K for both GEMMs)
#define VT_STRIDE 640
#define QT_TILES 37
#define SCALE_F 0.125f

typedef __bf16 bf16x8 __attribute__((ext_vector_type(8)));
typedef float f32x4 __attribute__((ext_vector_type(4)));
typedef unsigned short u16x8 __attribute__((ext_vector_type(8)));

__device__ __forceinline__ unsigned short f2bf(float f) {
    unsigned int u = __builtin_bit_cast(unsigned int, f);
    return (unsigned short)((u + 0x7fffu + ((u >> 16) & 1u)) >> 16);  // RNE
}

__device__ __forceinline__ f32x4 mfma16(bf16x8 a, bf16x8 b, f32x4 c) {
    return __builtin_amdgcn_mfma_f32_16x16x32_bf16(a, b, c, 0, 0, 0);
}

__device__ __forceinline__ void gll16(const void* g, void* l) {
    __builtin_amdgcn_global_load_lds(
        (const __attribute__((address_space(1))) void*)g,
        (__attribute__((address_space(3))) void*)l, 16, 0, 0);
}

// ---------------- fp32 -> bf16 bulk convert (vectorized, grid-stride)
__global__ __launch_bounds__(256) void cvt_bf16(
    const float* __restrict__ src, unsigned short* __restrict__ dst, int n8)
{
    int i = blockIdx.x * blockDim.x + threadIdx.x;
    int stride = gridDim.x * blockDim.x;
    for (; i < n8; i += stride) {
        const float* p = src + (size_t)i * 8;
        f32x4 v0 = *(const f32x4*)p;
        f32x4 v1 = *(const f32x4*)(p + 4);
        u16x8 u;
        u[0] = f2bf(v0[0]); u[1] = f2bf(v0[1]); u[2] = f2bf(v0[2]); u[3] = f2bf(v0[3]);
        u[4] = f2bf(v1[0]); u[5] = f2bf(v1[1]); u[6] = f2bf(v1[2]); u[7] = f2bf(v1[3]);
        *(u16x8*)(dst + (size_t)i * 8) = u;
    }
}

// ---------------- shared 128x128x(BK=32) bf16 mainloop (m97 structure)
// As/Bs: [128][32] u16 linear. A rows clamped to MROWS-1. Returns acc[4][4].
#define GEMM_MAINLOOP(A_PTR, B_PTR, MCLAMP)                                        \
    const int tid = threadIdx.x;                                                   \
    const int wv = tid >> 6, lane = tid & 63;                                      \
    const int lo = lane & 15, hi = lane >> 4;                                      \
    const int wr = wv >> 1, wc = wv & 1;                                           \
    f32x4 acc[4][4];                                                               \
    _Pragma("unroll") for (int i = 0; i < 4; ++i)                                  \
        _Pragma("unroll") for (int j = 0; j < 4; ++j)                              \
            acc[i][j] = (f32x4){0.f, 0.f, 0.f, 0.f};                               \
    const int c0 = wv * 128 + lane;       /* chunk idx, j=0 */                     \
    const int c1 = c0 + 64;               /* chunk idx, j=1 */                     \
    const int rA0 = c0 >> 2, kA0 = (c0 & 3) * 8;                                   \
    const int rA1 = c1 >> 2, kA1 = (c1 & 3) * 8;                                   \
    int gra0 = mt * 128 + rA0; if (MCLAMP && gra0 >= MROWS) gra0 = MROWS - 1;      \
    int gra1 = mt * 128 + rA1; if (MCLAMP && gra1 >= MROWS) gra1 = MROWS - 1;      \
    const int grb0 = nt * 128 + rA0, grb1 = nt * 128 + rA1;                        \
    unsigned short* As_d0 = As + (size_t)c0 * 8;                                   \
    unsigned short* As_d1 = As + (size_t)c1 * 8;                                   \
    unsigned short* Bs_d0 = Bs + (size_t)c0 * 8;                                   \
    unsigned short* Bs_d1 = Bs + (size_t)c1 * 8;                                   \
    for (int k0 = 0; k0 < KDIM; k0 += 32) {                                        \
        gll16(A_PTR + (size_t)gra0 * KDIM + k0 + kA0, As_d0);                      \
        gll16(A_PTR + (size_t)gra1 * KDIM + k0 + kA1, As_d1);                      \
        gll16(B_PTR + (size_t)grb0 * KDIM + k0 + kA0, Bs_d0);                      \
        gll16(B_PTR + (size_t)grb1 * KDIM + k0 + kA1, Bs_d1);                      \
        __syncthreads();                                                           \
        bf16x8 af[4], bfr[4];                                                      \
        _Pragma("unroll") for (int mi = 0; mi < 4; ++mi)                           \
            af[mi] = *(const bf16x8*)(As + (wr * 64 + mi * 16 + lo) * 32 + hi * 8);\
        _Pragma("unroll") for (int nj = 0; nj < 4; ++nj)                           \
            bfr[nj] = *(const bf16x8*)(Bs + (wc * 64 + nj * 16 + lo) * 32 + hi * 8);\
        _Pragma("unroll") for (int mi = 0; mi < 4; ++mi)                           \
            _Pragma("unroll") for (int nj = 0; nj < 4; ++nj)                       \
                acc[mi][nj] = mfma16(af[mi], bfr[nj], acc[mi][nj]);                \
        __syncthreads();                                                           \
    }

// ---------------- Stage 1: QKV GEMM, epilogue scatters q,k [B,H,N,64], V^T [B,H,64,640]
__global__ __launch_bounds__(256) void qkv_gemm(
    const unsigned short* __restrict__ A,   // x bf16 [18464][768]
    const unsigned short* __restrict__ Bm,  // qkv_w bf16 [2304][768]
    unsigned short* __restrict__ qb,
    unsigned short* __restrict__ kb,
    unsigned short* __restrict__ vtb)
{
    __shared__ unsigned short As[128 * 32];
    __shared__ unsigned short Bs[128 * 32];
    const int NT = 18;
    int nt = blockIdx.x % NT, mt = blockIdx.x / NT;

    GEMM_MAINLOOP(A, Bm, 1)

    // epilogue: s = nt/6 (q/k/v), h = (nt%6)*2 + wc, d = nj*16 + lo
    const int s = nt / 6;
    const int h = (nt % 6) * 2 + wc;
#pragma unroll
    for (int mi = 0; mi < 4; ++mi) {
#pragma unroll
        for (int r = 0; r < 4; ++r) {
            int m = mt * 128 + wr * 64 + mi * 16 + hi * 4 + r;
            if (m >= MROWS) continue;
            int b = m / NQ, n = m % NQ;
            size_t bh = (size_t)(b * NH + h);
#pragma unroll
            for (int nj = 0; nj < 4; ++nj) {
                int d = nj * 16 + lo;
                unsigned short bv = f2bf(acc[mi][nj][r]);
                if (s == 0)      qb[(bh * NQ + n) * HDIM + d] = bv;
                else if (s == 1) kb[(bh * NQ + n) * HDIM + d] = bv;
                else             vtb[(bh * HDIM + d) * VT_STRIDE + n] = bv;
            }
        }
    }
}

// ---------------- Stage 3: proj GEMM, fp32 out + bias
__global__ __launch_bounds__(256) void proj_gemm(
    const unsigned short* __restrict__ A,   // attn out bf16 [18464][768]
    const unsigned short* __restrict__ Bm,  // proj_w bf16 [768][768]
    const float* __restrict__ bias,
    float* __restrict__ out)
{
    __shared__ unsigned short As[128 * 32];
    __shared__ unsigned short Bs[128 * 32];
    const int NT = 6;
    int nt = blockIdx.x % NT, mt = blockIdx.x / NT;

    GEMM_MAINLOOP(A, Bm, 1)

    float bv[4];
#pragma unroll
    for (int nj = 0; nj < 4; ++nj) bv[nj] = bias[nt * 128 + wc * 64 + nj * 16 + lo];
#pragma unroll
    for (int mi = 0; mi < 4; ++mi)
#pragma unroll
        for (int r = 0; r < 4; ++r) {
            int m = mt * 128 + wr * 64 + mi * 16 + hi * 4 + r;
            if (m >= MROWS) continue;
#pragma unroll
            for (int nj = 0; nj < 4; ++nj)
                out[(size_t)m * CDIM + nt * 128 + wc * 64 + nj * 16 + lo] =
                    acc[mi][nj][r] + bv[nj];
        }
}

// ---------------- Stage 2: flash attention, 1 wave per (b,h,16-row q-tile); NO cross-wave sync
__global__ __launch_bounds__(256) void attn_fused(
    const unsigned short* __restrict__ qb,
    const unsigned short* __restrict__ kb,
    const unsigned short* __restrict__ vtb,
    const float* __restrict__ mask,     // [12][577][577] fp32
    unsigned short* __restrict__ ob)    // [B][577][768] bf16
{
    __shared__ unsigned short P_lds[4][16][72];  // wave-private slices, pad->2-way alias only
    const int wv = threadIdx.x >> 6;
    const int lane = threadIdx.x & 63;
    const int lo = lane & 15, hi = lane >> 4;
    int bh = blockIdx.x / 10;
    int qt = (blockIdx.x % 10) * 4 + wv;
    bool valid = qt < QT_TILES;
    if (qt > QT_TILES - 1) qt = QT_TILES - 1;
    int h = bh % NH, b = bh / NH;

    const unsigned short* qp = qb + (size_t)bh * NQ * HDIM;
    const unsigned short* kp = kb + (size_t)bh * NQ * HDIM;
    const unsigned short* vp = vtb + (size_t)bh * HDIM * VT_STRIDE;
    const float* mp = mask + (size_t)h * NQ * NQ;

    int qr = qt * 16 + lo; if (qr > NQ - 1) qr = NQ - 1;
    bf16x8 aq0 = *(const bf16x8*)(qp + (size_t)qr * HDIM + 8 * hi);
    bf16x8 aq1 = *(const bf16x8*)(qp + (size_t)qr * HDIM + 32 + 8 * hi);

    float m_run[4], l_run[4];
    f32x4 accO[4];
#pragma unroll
    for (int r = 0; r < 4; ++r) { m_run[r] = -1e30f; l_run[r] = 0.f; }
#pragma unroll
    for (int dj = 0; dj < 4; ++dj) accO[dj] = (f32x4){0.f, 0.f, 0.f, 0.f};

    const int qrowbase = qt * 16 + hi * 4;

    for (int kv0 = 0; kv0 < NQ; kv0 += 64) {
        f32x4 S[4];
#pragma unroll
        for (int nj = 0; nj < 4; ++nj) {
            int kc = kv0 + nj * 16 + lo; if (kc > NQ - 1) kc = NQ - 1;
            bf16x8 bk0 = *(const bf16x8*)(kp + (size_t)kc * HDIM + 8 * hi);
            bf16x8 bk1 = *(const bf16x8*)(kp + (size_t)kc * HDIM + 32 + 8 * hi);
            f32x4 sv = (f32x4){0.f, 0.f, 0.f, 0.f};
            sv = mfma16(aq0, bk0, sv);
            sv = mfma16(aq1, bk1, sv);
            S[nj] = sv;
        }
#pragma unroll
        for (int nj = 0; nj < 4; ++nj) {
            int col = kv0 + nj * 16 + lo;
            if (col < NQ) {
#pragma unroll
                for (int r = 0; r < 4; ++r) {
                    int rowc = qrowbase + r; if (rowc > NQ - 1) rowc = NQ - 1;
                    S[nj][r] = S[nj][r] * SCALE_F + mp[(size_t)rowc * NQ + col];
                }
            } else {
#pragma unroll
                for (int r = 0; r < 4; ++r) S[nj][r] = -1e30f;
            }
        }
#pragma unroll
        for (int r = 0; r < 4; ++r) {
            float mx = fmaxf(fmaxf(S[0][r], S[1][r]), fmaxf(S[2][r], S[3][r]));
            mx = fmaxf(mx, __shfl_xor(mx, 1));
            mx = fmaxf(mx, __shfl_xor(mx, 2));
            mx = fmaxf(mx, __shfl_xor(mx, 4));
            mx = fmaxf(mx, __shfl_xor(mx, 8));
            float mnew = fmaxf(m_run[r], mx);
            float corr = __expf(m_run[r] - mnew);
            m_run[r] = mnew;
            l_run[r] *= corr;
            accO[0][r] *= corr; accO[1][r] *= corr;
            accO[2][r] *= corr; accO[3][r] *= corr;
            float ps = 0.f;
#pragma unroll
            for (int nj = 0; nj < 4; ++nj) {
                float p = __expf(S[nj][r] - mnew);
                ps += p;
                P_lds[wv][hi * 4 + r][nj * 16 + lo] = f2bf(p);
            }
            ps += __shfl_xor(ps, 1);
            ps += __shfl_xor(ps, 2);
            ps += __shfl_xor(ps, 4);
            ps += __shfl_xor(ps, 8);
            l_run[r] += ps;
        }
        // wave-private LDS round-trip: intra-wave lgkmcnt ordering suffices (no barrier)
        bf16x8 pa0 = *(const bf16x8*)(&P_lds[wv][lo][8 * hi]);
        bf16x8 pa1 = *(const bf16x8*)(&P_lds[wv][lo][32 + 8 * hi]);
#pragma unroll
        for (int dj = 0; dj < 4; ++dj) {
            const unsigned short* vrow = vp + (size_t)(dj * 16 + lo) * VT_STRIDE + kv0;
            bf16x8 bv0 = *(const bf16x8*)(vrow + 8 * hi);
            bf16x8 bv1 = *(const bf16x8*)(vrow + 32 + 8 * hi);
            accO[dj] = mfma16(pa0, bv0, accO[dj]);
            accO[dj] = mfma16(pa1, bv1, accO[dj]);
        }
    }

    if (valid) {
#pragma unroll
        for (int r = 0; r < 4; ++r) {
            int row = qt * 16 + hi * 4 + r;
            if (row >= NQ) continue;
            float inv = 1.0f / l_run[r];
            size_t base = ((size_t)b * NQ + row) * CDIM + h * HDIM;
#pragma unroll
            for (int dj = 0; dj < 4; ++dj)
                ob[base + dj * 16 + lo] = f2bf(accO[dj][r] * inv);
        }
    }
}

extern "C" void kernel_launch(void* const* d_in, const int* in_sizes, int n_in,
                              void* d_out, int out_size, void* d_ws, size_t ws_size,
                              hipStream_t stream) {
    (void)in_sizes; (void)n_in; (void)out_size; (void)ws_size;
    const float* x      = (const float*)d_in[0];
    const float* qkv_w  = (const float*)d_in[1];
    const float* proj_w = (const float*)d_in[2];
    const float* proj_b = (const float*)d_in[3];
    const float* mask   = (const float*)d_in[4];
    float* out = (float*)d_out;

    const size_t x_elems  = (size_t)MROWS * CDIM;                 // 14,180,352
    const size_t w_elems  = (size_t)3 * CDIM * CDIM;              //  1,769,472
    const size_t pw_elems = (size_t)CDIM * CDIM;                  //    589,824
    const size_t qk_elems = (size_t)B_SZ * NH * NQ * HDIM;        // 14,180,352
    const size_t vt_elems = (size_t)B_SZ * NH * HDIM * VT_STRIDE; // 15,728,640

    unsigned short* xb    = (unsigned short*)d_ws;       // also aliased as attn-out
    unsigned short* wb    = xb + x_elems;
    unsigned short* pwb   = wb + w_elems;
    unsigned short* qbuf  = pwb + pw_elems;
    unsigned short* kbuf  = qbuf + qk_elems;
    unsigned short* vtbuf = kbuf + qk_elems;
    unsigned short* aobuf = xb;  // x_bf16 dead after stage 1 -> reuse (same size)
    // total ws use: ~115.6 MiB

    cvt_bf16<<<1024, 256, 0, stream>>>(x, xb, (int)(x_elems / 8));
    cvt_bf16<<<256, 256, 0, stream>>>(qkv_w, wb, (int)(w_elems / 8));
    cvt_bf16<<<128, 256, 0, stream>>>(proj_w, pwb, (int)(pw_elems / 8));
    qkv_gemm<<<145 * 18, 256, 0, stream>>>(xb, wb, qbuf, kbuf, vtbuf);
    attn_fused<<<B_SZ * NH * 10, 256, 0, stream>>>(qbuf, kbuf, vtbuf, mask, aobuf);
    proj_gemm<<<145 * 6, 256, 0, stream>>>(aobuf, pwb, proj_b, out);
}

// Round 3
// 498.277 us; speedup vs baseline: 1.9460x; 1.0151x over previous
//
#include <hip/hip_runtime.h>
#include <stdint.h>
#include <stddef.h>

#define B_SZ 32
#define NQ 577
#define CDIM 768
#define NH 12
#define HDIM 64
#define MROWS (B_SZ * NQ)     // 18464
#define KDIM CDIM             // 768
#define VT_STRIDE 640
#define MS_STRIDE 600         // mask LDS stride: keeps 4-row-apart aliasing to 2-way
#define SCALE_F 0.125f

typedef __bf16 bf16x8 __attribute__((ext_vector_type(8)));
typedef float f32x4 __attribute__((ext_vector_type(4)));
typedef unsigned short u16x8 __attribute__((ext_vector_type(8)));

__device__ __forceinline__ unsigned short f2bf(float f) {
    unsigned int u = __builtin_bit_cast(unsigned int, f);
    return (unsigned short)((u + 0x7fffu + ((u >> 16) & 1u)) >> 16);  // RNE
}
__device__ __forceinline__ float bf2f(unsigned short u) {
    unsigned int v = ((unsigned int)u) << 16;
    return __builtin_bit_cast(float, v);
}

__device__ __forceinline__ f32x4 mfma16(bf16x8 a, bf16x8 b, f32x4 c) {
    return __builtin_amdgcn_mfma_f32_16x16x32_bf16(a, b, c, 0, 0, 0);
}

__device__ __forceinline__ void gll16(const void* g, void* l) {
    __builtin_amdgcn_global_load_lds(
        (const __attribute__((address_space(1))) void*)g,
        (__attribute__((address_space(3))) void*)l, 16, 0, 0);
}

// ---------------- fp32 -> bf16 bulk convert
__global__ __launch_bounds__(256) void cvt_bf16(
    const float* __restrict__ src, unsigned short* __restrict__ dst, int n8)
{
    int i = blockIdx.x * blockDim.x + threadIdx.x;
    int stride = gridDim.x * blockDim.x;
    for (; i < n8; i += stride) {
        const float* p = src + (size_t)i * 8;
        f32x4 v0 = *(const f32x4*)p;
        f32x4 v1 = *(const f32x4*)(p + 4);
        u16x8 u;
        u[0] = f2bf(v0[0]); u[1] = f2bf(v0[1]); u[2] = f2bf(v0[2]); u[3] = f2bf(v0[3]);
        u[4] = f2bf(v1[0]); u[5] = f2bf(v1[1]); u[6] = f2bf(v1[2]); u[7] = f2bf(v1[3]);
        *(u16x8*)(dst + (size_t)i * 8) = u;
    }
}

// ---------------- shared 128x128x(BK=32) bf16 mainloop (m97 structure)
#define GEMM_MAINLOOP(A_PTR, B_PTR, MCLAMP)                                        \
    const int tid = threadIdx.x;                                                   \
    const int wv = tid >> 6, lane = tid & 63;                                      \
    const int lo = lane & 15, hi = lane >> 4;                                      \
    const int wr = wv >> 1, wc = wv & 1;                                           \
    f32x4 acc[4][4];                                                               \
    _Pragma("unroll") for (int i = 0; i < 4; ++i)                                  \
        _Pragma("unroll") for (int j = 0; j < 4; ++j)                              \
            acc[i][j] = (f32x4){0.f, 0.f, 0.f, 0.f};                               \
    const int c0 = wv * 128 + lane;                                                \
    const int c1 = c0 + 64;                                                        \
    const int rA0 = c0 >> 2, kA0 = (c0 & 3) * 8;                                   \
    const int rA1 = c1 >> 2, kA1 = (c1 & 3) * 8;                                   \
    int gra0 = mt * 128 + rA0; if (MCLAMP && gra0 >= MROWS) gra0 = MROWS - 1;      \
    int gra1 = mt * 128 + rA1; if (MCLAMP && gra1 >= MROWS) gra1 = MROWS - 1;      \
    const int grb0 = nt * 128 + rA0, grb1 = nt * 128 + rA1;                        \
    unsigned short* As_d0 = As + (size_t)c0 * 8;                                   \
    unsigned short* As_d1 = As + (size_t)c1 * 8;                                   \
    unsigned short* Bs_d0 = Bs + (size_t)c0 * 8;                                   \
    unsigned short* Bs_d1 = Bs + (size_t)c1 * 8;                                   \
    for (int k0 = 0; k0 < KDIM; k0 += 32) {                                        \
        gll16(A_PTR + (size_t)gra0 * KDIM + k0 + kA0, As_d0);                      \
        gll16(A_PTR + (size_t)gra1 * KDIM + k0 + kA1, As_d1);                      \
        gll16(B_PTR + (size_t)grb0 * KDIM + k0 + kA0, Bs_d0);                      \
        gll16(B_PTR + (size_t)grb1 * KDIM + k0 + kA1, Bs_d1);                      \
        __syncthreads();                                                           \
        bf16x8 af[4], bfr[4];                                                      \
        _Pragma("unroll") for (int mi = 0; mi < 4; ++mi)                           \
            af[mi] = *(const bf16x8*)(As + (wr * 64 + mi * 16 + lo) * 32 + hi * 8);\
        _Pragma("unroll") for (int nj = 0; nj < 4; ++nj)                           \
            bfr[nj] = *(const bf16x8*)(Bs + (wc * 64 + nj * 16 + lo) * 32 + hi * 8);\
        _Pragma("unroll") for (int mi = 0; mi < 4; ++mi)                           \
            _Pragma("unroll") for (int nj = 0; nj < 4; ++nj)                       \
                acc[mi][nj] = mfma16(af[mi], bfr[nj], acc[mi][nj]);                \
        __syncthreads();                                                           \
    }

// ---------------- Stage 1: QKV GEMM
__global__ __launch_bounds__(256) void qkv_gemm(
    const unsigned short* __restrict__ A,
    const unsigned short* __restrict__ Bm,
    unsigned short* __restrict__ qb,
    unsigned short* __restrict__ kb,
    unsigned short* __restrict__ vtb)
{
    __shared__ unsigned short As[128 * 32];
    __shared__ unsigned short Bs[128 * 32];
    const int NT = 18;
    int nt = blockIdx.x % NT, mt = blockIdx.x / NT;

    GEMM_MAINLOOP(A, Bm, 1)

    const int s = nt / 6;
    const int h = (nt % 6) * 2 + wc;
#pragma unroll
    for (int mi = 0; mi < 4; ++mi) {
#pragma unroll
        for (int r = 0; r < 4; ++r) {
            int m = mt * 128 + wr * 64 + mi * 16 + hi * 4 + r;
            if (m >= MROWS) continue;
            int b = m / NQ, n = m % NQ;
            size_t bh = (size_t)(b * NH + h);
#pragma unroll
            for (int nj = 0; nj < 4; ++nj) {
                int d = nj * 16 + lo;
                unsigned short bv = f2bf(acc[mi][nj][r]);
                if (s == 0)      qb[(bh * NQ + n) * HDIM + d] = bv;
                else if (s == 1) kb[(bh * NQ + n) * HDIM + d] = bv;
                else             vtb[(bh * HDIM + d) * VT_STRIDE + n] = bv;
            }
        }
    }
}

// ---------------- Stage 3: proj GEMM
__global__ __launch_bounds__(256) void proj_gemm(
    const unsigned short* __restrict__ A,
    const unsigned short* __restrict__ Bm,
    const float* __restrict__ bias,
    float* __restrict__ out)
{
    __shared__ unsigned short As[128 * 32];
    __shared__ unsigned short Bs[128 * 32];
    const int NT = 6;
    int nt = blockIdx.x % NT, mt = blockIdx.x / NT;

    GEMM_MAINLOOP(A, Bm, 1)

    float bv[4];
#pragma unroll
    for (int nj = 0; nj < 4; ++nj) bv[nj] = bias[nt * 128 + wc * 64 + nj * 16 + lo];
#pragma unroll
    for (int mi = 0; mi < 4; ++mi)
#pragma unroll
        for (int r = 0; r < 4; ++r) {
            int m = mt * 128 + wr * 64 + mi * 16 + hi * 4 + r;
            if (m >= MROWS) continue;
#pragma unroll
            for (int nj = 0; nj < 4; ++nj)
                out[(size_t)m * CDIM + nt * 128 + wc * 64 + nj * 16 + lo] =
                    acc[mi][nj][r] + bv[nj];
        }
}

// ---------------- Stage 2: flash attention
// Block = (h, qt, batch-group-of-8). Mask slice staged to LDS once (bf16),
// 4 waves x 2 sequential batches each; no cross-wave sync after staging.
__global__ __launch_bounds__(256) void attn_fused(
    const unsigned short* __restrict__ qb,
    const unsigned short* __restrict__ kb,
    const unsigned short* __restrict__ vtb,
    const float* __restrict__ mask,     // [12][577][577] fp32
    unsigned short* __restrict__ ob)    // [B][577][768] bf16
{
    __shared__ unsigned short mask_s[16][MS_STRIDE];   // bf16 mask slice
    __shared__ unsigned short P_lds[4][16][72];        // wave-private
    const int tid = threadIdx.x;
    const int wv = tid >> 6;
    const int lane = tid & 63;
    const int lo = lane & 15, hi = lane >> 4;

    const int bg = blockIdx.x & 3;
    const int rest = blockIdx.x >> 2;
    const int qt = rest % 37;
    const int h = rest / 37;

    // ---- stage mask slice [qt*16 .. qt*16+15][0..576] -> bf16 LDS
    const float* mp = mask + (size_t)h * NQ * NQ;
    for (int idx = tid; idx < 16 * 145; idx += 256) {
        int row = idx / 145, c4 = (idx % 145) * 4;
        int grow = qt * 16 + row; if (grow > NQ - 1) grow = NQ - 1;
        const float* src = mp + (size_t)grow * NQ + c4;
#pragma unroll
        for (int j = 0; j < 4; ++j) {
            int c = c4 + j;
            if (c < NQ) mask_s[row][c] = f2bf(src[j]);
        }
    }
    __syncthreads();

    const int qrl = hi * 4;   // local q-row base for this quarter-wave

    for (int bi = 0; bi < 2; ++bi) {
        const int b = bg * 8 + wv * 2 + bi;
        const size_t bh = (size_t)b * NH + h;
        const unsigned short* qp = qb + bh * NQ * HDIM;
        const unsigned short* kp = kb + bh * NQ * HDIM;
        const unsigned short* vp = vtb + bh * HDIM * VT_STRIDE;

        int qr = qt * 16 + lo; if (qr > NQ - 1) qr = NQ - 1;
        bf16x8 aq0 = *(const bf16x8*)(qp + (size_t)qr * HDIM + 8 * hi);
        bf16x8 aq1 = *(const bf16x8*)(qp + (size_t)qr * HDIM + 32 + 8 * hi);

        float m_run[4], l_run[4];
        f32x4 accO[4];
#pragma unroll
        for (int r = 0; r < 4; ++r) { m_run[r] = -1e30f; l_run[r] = 0.f; }
#pragma unroll
        for (int dj = 0; dj < 4; ++dj) accO[dj] = (f32x4){0.f, 0.f, 0.f, 0.f};

        for (int kv0 = 0; kv0 < NQ; kv0 += 64) {
            f32x4 S[4];
#pragma unroll
            for (int nj = 0; nj < 4; ++nj) {
                int kc = kv0 + nj * 16 + lo; if (kc > NQ - 1) kc = NQ - 1;
                bf16x8 bk0 = *(const bf16x8*)(kp + (size_t)kc * HDIM + 8 * hi);
                bf16x8 bk1 = *(const bf16x8*)(kp + (size_t)kc * HDIM + 32 + 8 * hi);
                f32x4 sv = (f32x4){0.f, 0.f, 0.f, 0.f};
                sv = mfma16(aq0, bk0, sv);
                sv = mfma16(aq1, bk1, sv);
                S[nj] = sv;
            }
#pragma unroll
            for (int nj = 0; nj < 4; ++nj) {
                int col = kv0 + nj * 16 + lo;
                if (col < NQ) {
#pragma unroll
                    for (int r = 0; r < 4; ++r)
                        S[nj][r] = S[nj][r] * SCALE_F + bf2f(mask_s[qrl + r][col]);
                } else {
#pragma unroll
                    for (int r = 0; r < 4; ++r) S[nj][r] = -1e30f;
                }
            }
#pragma unroll
            for (int r = 0; r < 4; ++r) {
                float mx = fmaxf(fmaxf(S[0][r], S[1][r]), fmaxf(S[2][r], S[3][r]));
                mx = fmaxf(mx, __shfl_xor(mx, 1));
                mx = fmaxf(mx, __shfl_xor(mx, 2));
                mx = fmaxf(mx, __shfl_xor(mx, 4));
                mx = fmaxf(mx, __shfl_xor(mx, 8));
                float mnew = fmaxf(m_run[r], mx);
                float corr = __expf(m_run[r] - mnew);
                m_run[r] = mnew;
                l_run[r] *= corr;
                accO[0][r] *= corr; accO[1][r] *= corr;
                accO[2][r] *= corr; accO[3][r] *= corr;
                float ps = 0.f;
#pragma unroll
                for (int nj = 0; nj < 4; ++nj) {
                    float p = __expf(S[nj][r] - mnew);
                    ps += p;
                    P_lds[wv][qrl + r][nj * 16 + lo] = f2bf(p);
                }
                ps += __shfl_xor(ps, 1);
                ps += __shfl_xor(ps, 2);
                ps += __shfl_xor(ps, 4);
                ps += __shfl_xor(ps, 8);
                l_run[r] += ps;
            }
            // wave-private LDS round-trip; intra-wave lgkmcnt ordering suffices
            bf16x8 pa0 = *(const bf16x8*)(&P_lds[wv][lo][8 * hi]);
            bf16x8 pa1 = *(const bf16x8*)(&P_lds[wv][lo][32 + 8 * hi]);
#pragma unroll
            for (int dj = 0; dj < 4; ++dj) {
                const unsigned short* vrow = vp + (size_t)(dj * 16 + lo) * VT_STRIDE + kv0;
                bf16x8 bv0 = *(const bf16x8*)(vrow + 8 * hi);
                bf16x8 bv1 = *(const bf16x8*)(vrow + 32 + 8 * hi);
                accO[dj] = mfma16(pa0, bv0, accO[dj]);
                accO[dj] = mfma16(pa1, bv1, accO[dj]);
            }
        }

#pragma unroll
        for (int r = 0; r < 4; ++r) {
            int row = qt * 16 + qrl + r;
            if (row >= NQ) continue;
            float inv = 1.0f / l_run[r];
            size_t base = ((size_t)b * NQ + row) * CDIM + h * HDIM;
#pragma unroll
            for (int dj = 0; dj < 4; ++dj)
                ob[base + dj * 16 + lo] = f2bf(accO[dj][r] * inv);
        }
    }
}

extern "C" void kernel_launch(void* const* d_in, const int* in_sizes, int n_in,
                              void* d_out, int out_size, void* d_ws, size_t ws_size,
                              hipStream_t stream) {
    (void)in_sizes; (void)n_in; (void)out_size; (void)ws_size;
    const float* x      = (const float*)d_in[0];
    const float* qkv_w  = (const float*)d_in[1];
    const float* proj_w = (const float*)d_in[2];
    const float* proj_b = (const float*)d_in[3];
    const float* mask   = (const float*)d_in[4];
    float* out = (float*)d_out;

    const size_t x_elems  = (size_t)MROWS * CDIM;                 // 14,180,352
    const size_t w_elems  = (size_t)3 * CDIM * CDIM;              //  1,769,472
    const size_t pw_elems = (size_t)CDIM * CDIM;                  //    589,824
    const size_t qk_elems = (size_t)B_SZ * NH * NQ * HDIM;        // 14,180,352
    const size_t vt_elems = (size_t)B_SZ * NH * HDIM * VT_STRIDE; // 15,728,640

    // vtbuf placed BEFORE qbuf so the benign 31-elem PV tail over-read of the
    // last (b,h) V^T row lands in qbuf (finite bf16), not past the allocation.
    unsigned short* xb    = (unsigned short*)d_ws;       // aliased as attn-out later
    unsigned short* wb    = xb + x_elems;
    unsigned short* pwb   = wb + w_elems;
    unsigned short* vtbuf = pwb + pw_elems;
    unsigned short* qbuf  = vtbuf + vt_elems;
    unsigned short* kbuf  = qbuf + qk_elems;
    unsigned short* aobuf = xb;  // x_bf16 dead after stage 1 -> reuse
    // total ws use: ~121.3 MB (same as round 2)

    cvt_bf16<<<1024, 256, 0, stream>>>(x, xb, (int)(x_elems / 8));
    cvt_bf16<<<256, 256, 0, stream>>>(qkv_w, wb, (int)(w_elems / 8));
    cvt_bf16<<<128, 256, 0, stream>>>(proj_w, pwb, (int)(pw_elems / 8));
    qkv_gemm<<<145 * 18, 256, 0, stream>>>(xb, wb, qbuf, kbuf, vtbuf);
    attn_fused<<<12 * 37 * 4, 256, 0, stream>>>(qbuf, kbuf, vtbuf, mask, aobuf);
    proj_gemm<<<145 * 6, 256, 0, stream>>>(aobuf, pwb, proj_b, out);
}

// Round 4
// 438.323 us; speedup vs baseline: 2.2121x; 1.1368x over previous
//
#include <hip/hip_runtime.h>
#include <stdint.h>
#include <stddef.h>

#define B_SZ 32
#define NQ 577
#define CDIM 768
#define NH 12
#define HDIM 64
#define MROWS (B_SZ * NQ)     // 18464
#define KDIM CDIM             // 768
#define VT_STRIDE 640
#define SCALE_F 0.125f

typedef __bf16 bf16x8 __attribute__((ext_vector_type(8)));
typedef float f32x4 __attribute__((ext_vector_type(4)));
typedef unsigned short u16x8 __attribute__((ext_vector_type(8)));
typedef unsigned short u16x4 __attribute__((ext_vector_type(4)));

__device__ __forceinline__ unsigned short f2bf(float f) {
    unsigned int u = __builtin_bit_cast(unsigned int, f);
    return (unsigned short)((u + 0x7fffu + ((u >> 16) & 1u)) >> 16);  // RNE
}
__device__ __forceinline__ float bf2f(unsigned short u) {
    unsigned int v = ((unsigned int)u) << 16;
    return __builtin_bit_cast(float, v);
}

__device__ __forceinline__ f32x4 mfma16(bf16x8 a, bf16x8 b, f32x4 c) {
    return __builtin_amdgcn_mfma_f32_16x16x32_bf16(a, b, c, 0, 0, 0);
}

__device__ __forceinline__ void gll16(const void* g, void* l) {
    __builtin_amdgcn_global_load_lds(
        (const __attribute__((address_space(1))) void*)g,
        (__attribute__((address_space(3))) void*)l, 16, 0, 0);
}

// ---------------- fp32 -> bf16 bulk convert
__global__ __launch_bounds__(256) void cvt_bf16(
    const float* __restrict__ src, unsigned short* __restrict__ dst, int n8)
{
    int i = blockIdx.x * blockDim.x + threadIdx.x;
    int stride = gridDim.x * blockDim.x;
    for (; i < n8; i += stride) {
        const float* p = src + (size_t)i * 8;
        f32x4 v0 = *(const f32x4*)p;
        f32x4 v1 = *(const f32x4*)(p + 4);
        u16x8 u;
        u[0] = f2bf(v0[0]); u[1] = f2bf(v0[1]); u[2] = f2bf(v0[2]); u[3] = f2bf(v0[3]);
        u[4] = f2bf(v1[0]); u[5] = f2bf(v1[1]); u[6] = f2bf(v1[2]); u[7] = f2bf(v1[3]);
        *(u16x8*)(dst + (size_t)i * 8) = u;
    }
}

// ---------------- shared 128x128x(BK=32) bf16 mainloop (m97 structure)
#define GEMM_MAINLOOP(A_PTR, B_PTR, MCLAMP)                                        \
    const int tid = threadIdx.x;                                                   \
    const int wv = tid >> 6, lane = tid & 63;                                      \
    const int lo = lane & 15, hi = lane >> 4;                                      \
    const int wr = wv >> 1, wc = wv & 1;                                           \
    f32x4 acc[4][4];                                                               \
    _Pragma("unroll") for (int i = 0; i < 4; ++i)                                  \
        _Pragma("unroll") for (int j = 0; j < 4; ++j)                              \
            acc[i][j] = (f32x4){0.f, 0.f, 0.f, 0.f};                               \
    const int c0 = wv * 128 + lane;                                                \
    const int c1 = c0 + 64;                                                        \
    const int rA0 = c0 >> 2, kA0 = (c0 & 3) * 8;                                   \
    const int rA1 = c1 >> 2, kA1 = (c1 & 3) * 8;                                   \
    int gra0 = mt * 128 + rA0; if (MCLAMP && gra0 >= MROWS) gra0 = MROWS - 1;      \
    int gra1 = mt * 128 + rA1; if (MCLAMP && gra1 >= MROWS) gra1 = MROWS - 1;      \
    const int grb0 = nt * 128 + rA0, grb1 = nt * 128 + rA1;                        \
    unsigned short* As_d0 = As + (size_t)c0 * 8;                                   \
    unsigned short* As_d1 = As + (size_t)c1 * 8;                                   \
    unsigned short* Bs_d0 = Bs + (size_t)c0 * 8;                                   \
    unsigned short* Bs_d1 = Bs + (size_t)c1 * 8;                                   \
    for (int k0 = 0; k0 < KDIM; k0 += 32) {                                        \
        gll16(A_PTR + (size_t)gra0 * KDIM + k0 + kA0, As_d0);                      \
        gll16(A_PTR + (size_t)gra1 * KDIM + k0 + kA1, As_d1);                      \
        gll16(B_PTR + (size_t)grb0 * KDIM + k0 + kA0, Bs_d0);                      \
        gll16(B_PTR + (size_t)grb1 * KDIM + k0 + kA1, Bs_d1);                      \
        __syncthreads();                                                           \
        bf16x8 af[4], bfr[4];                                                      \
        _Pragma("unroll") for (int mi = 0; mi < 4; ++mi)                           \
            af[mi] = *(const bf16x8*)(As + (wr * 64 + mi * 16 + lo) * 32 + hi * 8);\
        _Pragma("unroll") for (int nj = 0; nj < 4; ++nj)                           \
            bfr[nj] = *(const bf16x8*)(Bs + (wc * 64 + nj * 16 + lo) * 32 + hi * 8);\
        _Pragma("unroll") for (int mi = 0; mi < 4; ++mi)                           \
            _Pragma("unroll") for (int nj = 0; nj < 4; ++nj)                       \
                acc[mi][nj] = mfma16(af[mi], bfr[nj], acc[mi][nj]);                \
        __syncthreads();                                                           \
    }

// ---------------- Stage 1: QKV GEMM
__global__ __launch_bounds__(256) void qkv_gemm(
    const unsigned short* __restrict__ A,
    const unsigned short* __restrict__ Bm,
    unsigned short* __restrict__ qb,
    unsigned short* __restrict__ kb,
    unsigned short* __restrict__ vtb)
{
    __shared__ unsigned short As[128 * 32];
    __shared__ unsigned short Bs[128 * 32];
    const int NT = 18;
    int nt = blockIdx.x % NT, mt = blockIdx.x / NT;

    GEMM_MAINLOOP(A, Bm, 1)

    const int s = nt / 6;
    const int h = (nt % 6) * 2 + wc;
#pragma unroll
    for (int mi = 0; mi < 4; ++mi) {
#pragma unroll
        for (int r = 0; r < 4; ++r) {
            int m = mt * 128 + wr * 64 + mi * 16 + hi * 4 + r;
            if (m >= MROWS) continue;
            int b = m / NQ, n = m % NQ;
            size_t bh = (size_t)(b * NH + h);
#pragma unroll
            for (int nj = 0; nj < 4; ++nj) {
                int d = nj * 16 + lo;
                unsigned short bv = f2bf(acc[mi][nj][r]);
                if (s == 0)      qb[(bh * NQ + n) * HDIM + d] = bv;
                else if (s == 1) kb[(bh * NQ + n) * HDIM + d] = bv;
                else             vtb[(bh * HDIM + d) * VT_STRIDE + n] = bv;
            }
        }
    }
}

// ---------------- Stage 3: proj GEMM
__global__ __launch_bounds__(256) void proj_gemm(
    const unsigned short* __restrict__ A,
    const unsigned short* __restrict__ Bm,
    const float* __restrict__ bias,
    float* __restrict__ out)
{
    __shared__ unsigned short As[128 * 32];
    __shared__ unsigned short Bs[128 * 32];
    const int NT = 6;
    int nt = blockIdx.x % NT, mt = blockIdx.x / NT;

    GEMM_MAINLOOP(A, Bm, 1)

    float bv[4];
#pragma unroll
    for (int nj = 0; nj < 4; ++nj) bv[nj] = bias[nt * 128 + wc * 64 + nj * 16 + lo];
#pragma unroll
    for (int mi = 0; mi < 4; ++mi)
#pragma unroll
        for (int r = 0; r < 4; ++r) {
            int m = mt * 128 + wr * 64 + mi * 16 + hi * 4 + r;
            if (m >= MROWS) continue;
#pragma unroll
            for (int nj = 0; nj < 4; ++nj)
                out[(size_t)m * CDIM + nt * 128 + wc * 64 + nj * 16 + lo] =
                    acc[mi][nj][r] + bv[nj];
        }
}

// ---------------- Stage 2: flash attention, swapped QK^T (S^T = K·Q), 8 waves/block
// Block = (h, qt, batch-group-of-8); wave w owns batch bg*8+w. Lane (lo,hi):
// q-row = lo, k-slots = 16*nj + 4*hi + r. Row softmax is in-register:
// 15 fmax + 2 shfl. P round-trips LDS (4x b64 write, 2x b128 read) to become
// the PV A-operand. accO rows are q = 4*hi + r (std D layout).
__global__ __launch_bounds__(512, 4) void attn_fused(
    const unsigned short* __restrict__ qb,
    const unsigned short* __restrict__ kb,
    const unsigned short* __restrict__ vtb,
    const float* __restrict__ mask,     // [12][577][577] fp32
    unsigned short* __restrict__ ob)    // [B][577][768] bf16
{
    __shared__ unsigned short mask_s[16][600];
    __shared__ unsigned short P_lds[8][16][68];
    const int tid = threadIdx.x;
    const int wv = tid >> 6;
    const int lane = tid & 63;
    const int lo = lane & 15, hi = lane >> 4;

    const int bg = blockIdx.x & 3;
    const int rest = blockIdx.x >> 2;
    const int qt = rest % 37;
    const int h = rest / 37;

    // stage mask slice [qt*16 .. +15][0..576] -> bf16 LDS (scalar, once/block)
    const float* mp = mask + (size_t)h * NQ * NQ;
    for (int i = tid; i < 16 * NQ; i += 512) {
        int row = i / NQ, c = i % NQ;
        int grow = qt * 16 + row; if (grow > NQ - 1) grow = NQ - 1;
        mask_s[row][c] = f2bf(mp[(size_t)grow * NQ + c]);
    }
    __syncthreads();

    const int b = bg * 8 + wv;
    const size_t bh = (size_t)b * NH + h;
    const unsigned short* qp = qb + bh * NQ * HDIM;
    const unsigned short* kp = kb + bh * NQ * HDIM;
    const unsigned short* vp = vtb + bh * HDIM * VT_STRIDE;

    int qr = qt * 16 + lo; if (qr > NQ - 1) qr = NQ - 1;
    const bf16x8 bq0 = *(const bf16x8*)(qp + (size_t)qr * HDIM + 8 * hi);
    const bf16x8 bq1 = *(const bf16x8*)(qp + (size_t)qr * HDIM + 32 + 8 * hi);

    float m_run = -1e30f, l_run = 0.f;
    f32x4 accO[4];
#pragma unroll
    for (int dj = 0; dj < 4; ++dj) accO[dj] = (f32x4){0.f, 0.f, 0.f, 0.f};

    for (int kv0 = 0; kv0 < NQ; kv0 += 64) {
        const bool tail = (kv0 + 64 > NQ);

        // K fragments (A-operand), rows kv0+16nj+lo
        bf16x8 af0[4], af1[4];
#pragma unroll
        for (int nj = 0; nj < 4; ++nj) {
            int kr = kv0 + 16 * nj + lo; if (kr > NQ - 1) kr = NQ - 1;
            const unsigned short* kro = kp + (size_t)kr * HDIM;
            af0[nj] = *(const bf16x8*)(kro + 8 * hi);
            af1[nj] = *(const bf16x8*)(kro + 32 + 8 * hi);
        }
        // V fragments hoisted (independent of softmax; overlaps under vmcnt)
        bf16x8 bv0[4], bv1[4];
#pragma unroll
        for (int dj = 0; dj < 4; ++dj) {
            const unsigned short* vrow = vp + (size_t)(dj * 16 + lo) * VT_STRIDE + kv0;
            bv0[dj] = *(const bf16x8*)(vrow + 8 * hi);
            bv1[dj] = *(const bf16x8*)(vrow + 32 + 8 * hi);
        }

        // QK^T (swapped): S^T[k][q]
        __builtin_amdgcn_s_setprio(1);
        f32x4 S[4];
#pragma unroll
        for (int nj = 0; nj < 4; ++nj) {
            f32x4 sv = (f32x4){0.f, 0.f, 0.f, 0.f};
            sv = mfma16(af0[nj], bq0, sv);
            sv = mfma16(af1[nj], bq1, sv);
            S[nj] = sv;
        }
        __builtin_amdgcn_s_setprio(0);

        // scale + mask (per-lane row = lo, cols = kv0+16nj+4hi+r)
        float p[16];
#pragma unroll
        for (int nj = 0; nj < 4; ++nj) {
            int mcol = kv0 + 16 * nj + 4 * hi;
            if (mcol > 596) mcol = 596;   // tail: clamp LDS addr; values masked below
            u16x4 mw = *(const u16x4*)&mask_s[lo][mcol];
#pragma unroll
            for (int r = 0; r < 4; ++r)
                p[nj * 4 + r] = S[nj][r] * SCALE_F + bf2f(mw[r]);
        }
        if (tail) {
            const int rem = NQ - kv0;
#pragma unroll
            for (int nj = 0; nj < 4; ++nj)
#pragma unroll
                for (int r = 0; r < 4; ++r)
                    if (16 * nj + 4 * hi + r >= rem) p[nj * 4 + r] = -1e30f;
        }

        // row max: in-register tree + 2 cross-hi shfls
        float m01 = fmaxf(p[0], p[1]),  m23 = fmaxf(p[2], p[3]);
        float m45 = fmaxf(p[4], p[5]),  m67 = fmaxf(p[6], p[7]);
        float m89 = fmaxf(p[8], p[9]),  mab = fmaxf(p[10], p[11]);
        float mcd = fmaxf(p[12], p[13]), mef = fmaxf(p[14], p[15]);
        float pmax = fmaxf(fmaxf(fmaxf(m01, m23), fmaxf(m45, m67)),
                           fmaxf(fmaxf(m89, mab), fmaxf(mcd, mef)));
        pmax = fmaxf(pmax, __shfl_xor(pmax, 16));
        pmax = fmaxf(pmax, __shfl_xor(pmax, 32));

        // defer-max (T13): only rescale when some row's max grew by > 8
        bool grow = pmax > m_run + 8.f;
        float mnew = grow ? pmax : m_run;
        float corr = __expf(m_run - mnew);   // == 1 when !grow
        m_run = mnew;
        if (__any((int)grow)) {
            float c0 = __shfl(corr, 4 * hi + 0);
            float c1 = __shfl(corr, 4 * hi + 1);
            float c2 = __shfl(corr, 4 * hi + 2);
            float c3 = __shfl(corr, 4 * hi + 3);
#pragma unroll
            for (int dj = 0; dj < 4; ++dj) {
                accO[dj][0] *= c0; accO[dj][1] *= c1;
                accO[dj][2] *= c2; accO[dj][3] *= c3;
            }
        }

        // exp + sum + pack P -> LDS
#pragma unroll
        for (int i = 0; i < 16; ++i) p[i] = __expf(p[i] - mnew);
        float ps = (((p[0] + p[1]) + (p[2] + p[3])) + ((p[4] + p[5]) + (p[6] + p[7])))
                 + (((p[8] + p[9]) + (p[10] + p[11])) + ((p[12] + p[13]) + (p[14] + p[15])));
#pragma unroll
        for (int nj = 0; nj < 4; ++nj) {
            u16x4 w;
            w[0] = f2bf(p[nj * 4 + 0]); w[1] = f2bf(p[nj * 4 + 1]);
            w[2] = f2bf(p[nj * 4 + 2]); w[3] = f2bf(p[nj * 4 + 3]);
            *(u16x4*)&P_lds[wv][lo][16 * nj + 4 * hi] = w;
        }
        ps += __shfl_xor(ps, 16);
        ps += __shfl_xor(ps, 32);
        l_run = l_run * corr + ps;

        // P back as PV A-operand (compiler orders via lgkmcnt; wave-private slice)
        const bf16x8 pa0 = *(const bf16x8*)&P_lds[wv][lo][8 * hi];
        const bf16x8 pa1 = *(const bf16x8*)&P_lds[wv][lo][32 + 8 * hi];

        __builtin_amdgcn_s_setprio(1);
#pragma unroll
        for (int dj = 0; dj < 4; ++dj) {
            accO[dj] = mfma16(pa0, bv0[dj], accO[dj]);
            accO[dj] = mfma16(pa1, bv1[dj], accO[dj]);
        }
        __builtin_amdgcn_s_setprio(0);
    }

    // epilogue: l lives at lane (lo = q-row); accO rows are q = 4hi+r
    float linv[4];
#pragma unroll
    for (int r = 0; r < 4; ++r) linv[r] = 1.0f / __shfl(l_run, 4 * hi + r);
#pragma unroll
    for (int r = 0; r < 4; ++r) {
        int row = qt * 16 + 4 * hi + r;
        if (row >= NQ) continue;
        size_t base = ((size_t)b * NQ + row) * CDIM + h * HDIM;
#pragma unroll
        for (int dj = 0; dj < 4; ++dj)
            ob[base + dj * 16 + lo] = f2bf(accO[dj][r] * linv[r]);
    }
}

extern "C" void kernel_launch(void* const* d_in, const int* in_sizes, int n_in,
                              void* d_out, int out_size, void* d_ws, size_t ws_size,
                              hipStream_t stream) {
    (void)in_sizes; (void)n_in; (void)out_size; (void)ws_size;
    const float* x      = (const float*)d_in[0];
    const float* qkv_w  = (const float*)d_in[1];
    const float* proj_w = (const float*)d_in[2];
    const float* proj_b = (const float*)d_in[3];
    const float* mask   = (const float*)d_in[4];
    float* out = (float*)d_out;

    const size_t x_elems  = (size_t)MROWS * CDIM;                 // 14,180,352
    const size_t w_elems  = (size_t)3 * CDIM * CDIM;              //  1,769,472
    const size_t pw_elems = (size_t)CDIM * CDIM;                  //    589,824
    const size_t qk_elems = (size_t)B_SZ * NH * NQ * HDIM;        // 14,180,352
    const size_t vt_elems = (size_t)B_SZ * NH * HDIM * VT_STRIDE; // 15,728,640

    unsigned short* xb    = (unsigned short*)d_ws;       // aliased as attn-out later
    unsigned short* wb    = xb + x_elems;
    unsigned short* pwb   = wb + w_elems;
    unsigned short* vtbuf = pwb + pw_elems;
    unsigned short* qbuf  = vtbuf + vt_elems;
    unsigned short* kbuf  = qbuf + qk_elems;
    unsigned short* aobuf = xb;  // x_bf16 dead after stage 1 -> reuse

    cvt_bf16<<<1024, 256, 0, stream>>>(x, xb, (int)(x_elems / 8));
    cvt_bf16<<<256, 256, 0, stream>>>(qkv_w, wb, (int)(w_elems / 8));
    cvt_bf16<<<128, 256, 0, stream>>>(proj_w, pwb, (int)(pw_elems / 8));
    qkv_gemm<<<145 * 18, 256, 0, stream>>>(xb, wb, qbuf, kbuf, vtbuf);
    attn_fused<<<12 * 37 * 4, 512, 0, stream>>>(qbuf, kbuf, vtbuf, mask, aobuf);
    proj_gemm<<<145 * 6, 256, 0, stream>>>(aobuf, pwb, proj_b, out);
}